// Round 1
// baseline (295.325 us; speedup 1.0000x reference)
//
#include <hip/hip_runtime.h>
#include <hip/hip_bf16.h>

typedef __bf16 bf16x8 __attribute__((ext_vector_type(8)));
typedef float  f32x4  __attribute__((ext_vector_type(4)));

union U16 { uint4 u; bf16x8 b; };

static __device__ __forceinline__ unsigned short f2bf(float f) {
    unsigned u = __float_as_uint(f);
    unsigned r = (u + 0x7fffu + ((u >> 16) & 1u)) >> 16;   // RNE to bf16
    return (unsigned short)r;
}
static __device__ __forceinline__ float bflo(unsigned u) { return __uint_as_float(u << 16); }
static __device__ __forceinline__ float bfhi(unsigned u) { return __uint_as_float(u & 0xffff0000u); }

// ---------------- repack: emb [16,R,R] fp32 -> [R*R] texels of 16 bf16 (32 B) ----------------
__global__ void repack_kernel(const float* __restrict__ emb, uint4* __restrict__ dst, int R) {
    int t = blockIdx.x * blockDim.x + threadIdx.x;
    int n = R * R;
    if (t >= n) return;
    unsigned v[16];
#pragma unroll
    for (int c = 0; c < 16; ++c) v[c] = f2bf(emb[c * n + t]);
    uint4 o0, o1;
    o0.x = v[0] | (v[1] << 16);  o0.y = v[2]  | (v[3] << 16);
    o0.z = v[4] | (v[5] << 16);  o0.w = v[6]  | (v[7] << 16);
    o1.x = v[8] | (v[9] << 16);  o1.y = v[10] | (v[11] << 16);
    o1.z = v[12] | (v[13] << 16); o1.w = v[14] | (v[15] << 16);
    dst[t * 2 + 0] = o0;
    dst[t * 2 + 1] = o1;
}

// ---------------- setup: pack W1[0:64,:44] into B-fragment layout + per-batch t-bias ----------
// bpack: [ks(2)][quad(4)][n(48)][j(8)] bf16 ; tbias: [8][48] fp32
__global__ void setup_kernel(const float* __restrict__ W1, const float* __restrict__ b1,
                             const float* __restrict__ t_feat,
                             unsigned short* __restrict__ bpack, float* __restrict__ tbias) {
    int tid = blockIdx.x * blockDim.x + threadIdx.x;
    if (tid >= 384) return;
    int n  = tid % 48;
    int q  = (tid / 48) & 3;
    int ks = tid / 192;
#pragma unroll
    for (int j = 0; j < 8; ++j) {
        int k = ks * 32 + q * 8 + j;                  // k in [0,64) = feature rows of W1
        float v = (n < 44) ? W1[k * 44 + n] : 0.0f;
        bpack[tid * 8 + j] = f2bf(v);
    }
    // tbias (independent reuse of tid as b*48+n)
    int b = tid / 48;
    float s = 0.0f;
    if (n < 44) {
        s = b1[n];
        for (int m = 0; m < 24; ++m) s += t_feat[b * 24 + m] * W1[(64 + m) * 44 + n];
    }
    tbias[tid] = s;
}

// ---------------- fused gather + MLP ----------------
__global__ __launch_bounds__(256, 4)
void fused_kernel(const float* __restrict__ coords,
                  const uint4* __restrict__ tab0, const uint4* __restrict__ tab1,
                  const uint4* __restrict__ tab2, const uint4* __restrict__ tab3,
                  const uint4* __restrict__ bpack,
                  const float* __restrict__ tbias,
                  const float* __restrict__ W2, const float* __restrict__ b2,
                  float2* __restrict__ out) {
    // per-point row: 64 bf16 feats + 8 bf16 pad = 144 B = 9 uint4 (stride 9 -> conflict-free b128)
    __shared__ uint4 sf[256 * 9];
    const int tid = threadIdx.x;
    const int pbase = blockIdx.x * 256;
    const int p = pbase + tid;
    const float2 xy = ((const float2*)coords)[p];

    const uint4* tabs[4] = {tab0, tab1, tab2, tab3};
#pragma unroll
    for (int l = 0; l < 4; ++l) {
        const int R = 64 << l;
        float fx = (xy.x + 1.0f) * 0.5f * (float)(R - 1);
        float fy = (xy.y + 1.0f) * 0.5f * (float)(R - 1);
        int ix = (int)floorf(fx);
        int iy = (int)floorf(fy);
        ix = max(0, min(ix, R - 2));
        iy = max(0, min(iy, R - 2));
        const float wx1 = fx - (float)ix, wy1 = fy - (float)iy;
        const float wx0 = 1.0f - wx1,    wy0 = 1.0f - wy1;
        const uint4* r0 = tabs[l] + (iy * R + ix) * 2;   // texel = 2 uint4 (16 bf16)
        const uint4* r1 = r0 + R * 2;
        const uint4 a0 = r0[0], a1 = r0[1], b0 = r0[2], b1v = r0[3];  // (y0,x0) (y0,x1)
        const uint4 c0 = r1[0], c1 = r1[1], d0 = r1[2], d1v = r1[3];  // (y1,x0) (y1,x1)

        auto comp = [&](unsigned ua, unsigned ub, unsigned uc, unsigned ud) -> unsigned {
            float lo = wy0 * (wx0 * bflo(ua) + wx1 * bflo(ub)) +
                       wy1 * (wx0 * bflo(uc) + wx1 * bflo(ud));
            float hi = wy0 * (wx0 * bfhi(ua) + wx1 * bfhi(ub)) +
                       wy1 * (wx0 * bfhi(uc) + wx1 * bfhi(ud));
            return (unsigned)f2bf(lo) | ((unsigned)f2bf(hi) << 16);
        };
        uint4 o0, o1;
        o0.x = comp(a0.x, b0.x, c0.x, d0.x);
        o0.y = comp(a0.y, b0.y, c0.y, d0.y);
        o0.z = comp(a0.z, b0.z, c0.z, d0.z);
        o0.w = comp(a0.w, b0.w, c0.w, d0.w);
        o1.x = comp(a1.x, b1v.x, c1.x, d1v.x);
        o1.y = comp(a1.y, b1v.y, c1.y, d1v.y);
        o1.z = comp(a1.z, b1v.z, c1.z, d1v.z);
        o1.w = comp(a1.w, b1v.w, c1.w, d1v.w);
        sf[tid * 9 + l * 2 + 0] = o0;   // k = l*16 .. l*16+15
        sf[tid * 9 + l * 2 + 1] = o1;
    }
    __syncthreads();

    const int w    = tid >> 6;
    const int L    = tid & 63;
    const int col  = L & 15;     // N index within tile / C-layout column
    const int quad = L >> 4;
    const int bat  = pbase >> 18;  // 512*512 points per batch; blocks never straddle

    // B fragments: lane holds B[k = ks*32+quad*8+j][n = nt*16+col]
    bf16x8 Bf[3][2];
#pragma unroll
    for (int nt = 0; nt < 3; ++nt)
#pragma unroll
        for (int ks = 0; ks < 2; ++ks) {
            U16 u; u.u = bpack[(ks * 4 + quad) * 48 + nt * 16 + col];
            Bf[nt][ks] = u.b;
        }

    float tb[3], w2v[3][2];
#pragma unroll
    for (int nt = 0; nt < 3; ++nt) {
        int c = nt * 16 + col;
        tb[nt] = tbias[bat * 48 + c];
        bool v = (c < 44);
        w2v[nt][0] = v ? W2[c * 2 + 0] : 0.0f;
        w2v[nt][1] = v ? W2[c * 2 + 1] : 0.0f;
    }
    const float b20 = b2[0], b21 = b2[1];

#pragma unroll
    for (int mt = 0; mt < 4; ++mt) {
        const uint4* arow = &sf[(w * 64 + mt * 16 + col) * 9];
        U16 ua0; ua0.u = arow[quad];       // k-step 0: k = quad*8 + j
        U16 ua1; ua1.u = arow[4 + quad];   // k-step 1: k = 32 + quad*8 + j
        f32x4 acc[3];
#pragma unroll
        for (int nt = 0; nt < 3; ++nt) {
            acc[nt] = (f32x4){0.0f, 0.0f, 0.0f, 0.0f};
            acc[nt] = __builtin_amdgcn_mfma_f32_16x16x32_bf16(ua0.b, Bf[nt][0], acc[nt], 0, 0, 0);
            acc[nt] = __builtin_amdgcn_mfma_f32_16x16x32_bf16(ua1.b, Bf[nt][1], acc[nt], 0, 0, 0);
        }
#pragma unroll
        for (int reg = 0; reg < 4; ++reg) {
            float s0 = 0.0f, s1 = 0.0f;
#pragma unroll
            for (int nt = 0; nt < 3; ++nt) {
                float h = acc[nt][reg] + tb[nt];          // C layout: row=(quad)*4+reg, col
                h = fmaxf(h, 0.01f * h);                   // leaky relu (slope < 1)
                s0 += h * w2v[nt][0];
                s1 += h * w2v[nt][1];
            }
#pragma unroll
            for (int m = 1; m < 16; m <<= 1) {             // reduce over 16 cols (lanes)
                s0 += __shfl_xor(s0, m, 64);
                s1 += __shfl_xor(s1, m, 64);
            }
            if (col == 0) {
                int pr = pbase + w * 64 + mt * 16 + quad * 4 + reg;
                float o0 = 1.0f / (1.0f + __expf(-(s0 + b20)));
                float o1 = 1.0f / (1.0f + __expf(-(s1 + b21)));
                out[pr] = make_float2(o0, o1);
            }
        }
    }
}

extern "C" void kernel_launch(void* const* d_in, const int* in_sizes, int n_in,
                              void* d_out, int out_size, void* d_ws, size_t ws_size,
                              hipStream_t stream) {
    const float* coords = (const float*)d_in[0];
    const float* t_feat = (const float*)d_in[1];
    const float* emb0   = (const float*)d_in[2];
    const float* emb1   = (const float*)d_in[3];
    const float* emb2   = (const float*)d_in[4];
    const float* emb3   = (const float*)d_in[5];
    const float* W1     = (const float*)d_in[6];
    const float* b1     = (const float*)d_in[7];
    const float* W2     = (const float*)d_in[8];
    const float* b2     = (const float*)d_in[9];

    char* ws = (char*)d_ws;
    uint4* tab0 = (uint4*)(ws + 0);          //  64^2 * 32 B = 131072
    uint4* tab1 = (uint4*)(ws + 131072);     // 128^2 * 32 B = 524288
    uint4* tab2 = (uint4*)(ws + 655360);     // 256^2 * 32 B = 2 MiB
    uint4* tab3 = (uint4*)(ws + 2752512);    // 512^2 * 32 B = 8 MiB
    uint4* bpack = (uint4*)(ws + 11141120);  // 6144 B
    float* tbias = (float*)(ws + 11147264);  // 1536 B

    repack_kernel<<<(64 * 64 + 255) / 256, 256, 0, stream>>>(emb0, tab0, 64);
    repack_kernel<<<(128 * 128 + 255) / 256, 256, 0, stream>>>(emb1, tab1, 128);
    repack_kernel<<<(256 * 256 + 255) / 256, 256, 0, stream>>>(emb2, tab2, 256);
    repack_kernel<<<(512 * 512 + 255) / 256, 256, 0, stream>>>(emb3, tab3, 512);
    setup_kernel<<<2, 256, 0, stream>>>(W1, b1, t_feat,
                                        (unsigned short*)bpack, tbias);
    fused_kernel<<<8192, 256, 0, stream>>>(coords, tab0, tab1, tab2, tab3,
                                           bpack, tbias, W2, b2, (float2*)d_out);
}

// Round 2
// 208.440 us; speedup vs baseline: 1.4168x; 1.4168x over previous
//
#include <hip/hip_runtime.h>
#include <hip/hip_bf16.h>

typedef __bf16 bf16x8 __attribute__((ext_vector_type(8)));
typedef float  f32x4  __attribute__((ext_vector_type(4)));
typedef float  f32x2  __attribute__((ext_vector_type(2)));

union U16 { uint4 u; bf16x8 b; };

#define EMB_SCALE 4096.0f
#define EMB_INV   (1.0f / 4096.0f)

static __device__ __forceinline__ unsigned f2bf(float f) {
    unsigned u = __float_as_uint(f);
    return (u + 0x7fffu + ((u >> 16) & 1u)) >> 16;   // RNE to bf16
}

static __device__ __forceinline__ unsigned pk8(float a, float b, float c, float d) {
    unsigned r = __builtin_amdgcn_cvt_pk_fp8_f32(a, b, 0u, false);
    r = __builtin_amdgcn_cvt_pk_fp8_f32(c, d, r, true);
    return r;
}

// ---- one prep kernel: repack 4 emb tables to fp8 texels + pack W1 fragments + t-bias + padded W2
// tab texel t = 16 fp8 (one uint4); level bases (texels): 0, 4096, 20480, 86016 (total 348160)
__global__ void prep_kernel(const float* __restrict__ emb0, const float* __restrict__ emb1,
                            const float* __restrict__ emb2, const float* __restrict__ emb3,
                            const float* __restrict__ W1, const float* __restrict__ b1,
                            const float* __restrict__ t_feat, const float* __restrict__ W2,
                            uint4* __restrict__ tab, unsigned short* __restrict__ bpack,
                            float* __restrict__ tbias, float* __restrict__ w2pad) {
    if (blockIdx.x < 1360) {
        int t = blockIdx.x * 256 + threadIdx.x;   // level boundaries are multiples of 256
        const float* e; int i, n;
        if (t < 4096)       { e = emb0; i = t;         n = 4096;   }
        else if (t < 20480) { e = emb1; i = t - 4096;  n = 16384;  }
        else if (t < 86016) { e = emb2; i = t - 20480; n = 65536;  }
        else                { e = emb3; i = t - 86016; n = 262144; }
        float v[16];
#pragma unroll
        for (int c = 0; c < 16; ++c) v[c] = e[c * n + i] * EMB_SCALE;
        uint4 o;
        o.x = pk8(v[0],  v[1],  v[2],  v[3]);
        o.y = pk8(v[4],  v[5],  v[6],  v[7]);
        o.z = pk8(v[8],  v[9],  v[10], v[11]);
        o.w = pk8(v[12], v[13], v[14], v[15]);
        tab[t] = o;
    } else {
        int tid = threadIdx.x;
        for (int s = tid; s < 384; s += 256) {
            int nn = s % 48;
            int q  = (s / 48) & 3;
            int ks = s / 192;
#pragma unroll
            for (int j = 0; j < 8; ++j) {
                int k = ks * 32 + q * 8 + j;               // W1 row (feature k)
                float v = (nn < 44) ? W1[k * 44 + nn] : 0.0f;
                bpack[s * 8 + j] = (unsigned short)f2bf(v);
            }
            int b = s / 48;                                 // batch 0..7 (384/48 = 8)
            float sum = 0.0f;
            if (nn < 44) {
                sum = b1[nn];
                for (int m = 0; m < 24; ++m) sum += t_feat[b * 24 + m] * W1[(64 + m) * 44 + nn];
            }
            tbias[s] = sum;
        }
        if (tid < 96) w2pad[tid] = (tid < 88) ? W2[tid] : 0.0f;  // rows 44..47 zero
    }
}

// ---- fused gather + MLP. GEMM orientation: D[m=hidden][n=point] = W1^T · x^T
// so the layer-2 reduction is across quads only (2 shuffles/value instead of 4).
__global__ __launch_bounds__(256, 4)
void fused_kernel(const float2* __restrict__ coords, const uint4* __restrict__ tab,
                  const uint4* __restrict__ bpack, const float* __restrict__ tbias,
                  const float* __restrict__ w2pad, const float* __restrict__ b2,
                  float2* __restrict__ out) {
    __shared__ uint4 sf[256 * 9];   // 64 bf16 feats + pad = 144 B/point (stride 9 -> conflict-free)
    const int tid = threadIdx.x;
    const int pbase = blockIdx.x * 256;
    const float2 xy = coords[pbase + tid];

    const int bases[4] = {0, 4096, 20480, 86016};
#pragma unroll
    for (int l = 0; l < 4; ++l) {
        const int R = 64 << l;
        float fx = (xy.x + 1.0f) * 0.5f * (float)(R - 1);
        float fy = (xy.y + 1.0f) * 0.5f * (float)(R - 1);
        int ix = (int)floorf(fx), iy = (int)floorf(fy);
        ix = max(0, min(ix, R - 2));
        iy = max(0, min(iy, R - 2));
        const float wx1 = fx - (float)ix, wy1 = fy - (float)iy;
        const float wx0 = 1.0f - wx1,    wy0 = 1.0f - wy1;
        const float wa = wy0 * wx0 * EMB_INV, wb = wy0 * wx1 * EMB_INV;
        const float wc = wy1 * wx0 * EMB_INV, wd = wy1 * wx1 * EMB_INV;
        const uint4* r0 = tab + bases[l] + iy * R + ix;
        const uint4* r1 = r0 + R;
        const uint4 A = r0[0], B = r0[1], C = r1[0], D = r1[1];

        auto icomp = [&](unsigned ua, unsigned ub, unsigned uc, unsigned ud,
                         unsigned &lo, unsigned &hi) {
            f32x2 a0 = __builtin_amdgcn_cvt_pk_f32_fp8(ua, false);
            f32x2 a1 = __builtin_amdgcn_cvt_pk_f32_fp8(ua, true);
            f32x2 bb0 = __builtin_amdgcn_cvt_pk_f32_fp8(ub, false);
            f32x2 bb1 = __builtin_amdgcn_cvt_pk_f32_fp8(ub, true);
            f32x2 c0 = __builtin_amdgcn_cvt_pk_f32_fp8(uc, false);
            f32x2 c1 = __builtin_amdgcn_cvt_pk_f32_fp8(uc, true);
            f32x2 d0 = __builtin_amdgcn_cvt_pk_f32_fp8(ud, false);
            f32x2 d1 = __builtin_amdgcn_cvt_pk_f32_fp8(ud, true);
            f32x2 rlo = wa * a0 + wb * bb0 + wc * c0 + wd * d0;
            f32x2 rhi = wa * a1 + wb * bb1 + wc * c1 + wd * d1;
            lo = f2bf(rlo.x) | (f2bf(rlo.y) << 16);
            hi = f2bf(rhi.x) | (f2bf(rhi.y) << 16);
        };
        uint4 o0, o1;
        icomp(A.x, B.x, C.x, D.x, o0.x, o0.y);   // ch 0..3
        icomp(A.y, B.y, C.y, D.y, o0.z, o0.w);   // ch 4..7
        icomp(A.z, B.z, C.z, D.z, o1.x, o1.y);   // ch 8..11
        icomp(A.w, B.w, C.w, D.w, o1.z, o1.w);   // ch 12..15
        sf[tid * 9 + l * 2 + 0] = o0;            // k = l*16 .. l*16+15
        sf[tid * 9 + l * 2 + 1] = o1;
    }
    __syncthreads();

    const int w    = tid >> 6;
    const int L    = tid & 63;
    const int col  = L & 15;     // = point-in-tile (C col) AND m-index of A-frag
    const int quad = L >> 4;
    const int bat  = pbase >> 18;   // 512*512 points per batch; blocks never straddle

    // A fragments: lane holds A[m = mt*16+col][k = ks*32+quad*8+j] = W1[k][mt*16+col]
    bf16x8 Af[3][2];
#pragma unroll
    for (int mt = 0; mt < 3; ++mt)
#pragma unroll
        for (int ks = 0; ks < 2; ++ks) {
            U16 u; u.u = bpack[(ks * 4 + quad) * 48 + mt * 16 + col];
            Af[mt][ks] = u.b;
        }

    // per-lane bias / W2 for its 12 hidden rows (rows 44..47 padded to zero)
    float tbv[3][4], w2a[3][4], w2b[3][4];
#pragma unroll
    for (int mt = 0; mt < 3; ++mt) {
        const float4 t4 = *(const float4*)&tbias[bat * 48 + mt * 16 + quad * 4];
        tbv[mt][0] = t4.x; tbv[mt][1] = t4.y; tbv[mt][2] = t4.z; tbv[mt][3] = t4.w;
        const float4 p0 = *(const float4*)&w2pad[(mt * 16 + quad * 4) * 2];
        const float4 p1 = *(const float4*)&w2pad[(mt * 16 + quad * 4) * 2 + 4];
        w2a[mt][0] = p0.x; w2b[mt][0] = p0.y;
        w2a[mt][1] = p0.z; w2b[mt][1] = p0.w;
        w2a[mt][2] = p1.x; w2b[mt][2] = p1.y;
        w2a[mt][3] = p1.z; w2b[mt][3] = p1.w;
    }
    const float b20 = b2[0], b21 = b2[1];

#pragma unroll
    for (int t = 0; t < 4; ++t) {    // 4 point-tiles of 16 per wave
        const uint4* brow = &sf[(w * 64 + t * 16 + col) * 9];
        U16 ub0; ub0.u = brow[quad];        // B[k=quad*8+j][n=col]
        U16 ub1; ub1.u = brow[4 + quad];    // k += 32
        f32x4 acc[3];
#pragma unroll
        for (int mt = 0; mt < 3; ++mt) {
            acc[mt] = (f32x4){0.0f, 0.0f, 0.0f, 0.0f};
            acc[mt] = __builtin_amdgcn_mfma_f32_16x16x32_bf16(Af[mt][0], ub0.b, acc[mt], 0, 0, 0);
            acc[mt] = __builtin_amdgcn_mfma_f32_16x16x32_bf16(Af[mt][1], ub1.b, acc[mt], 0, 0, 0);
        }
        float s0 = 0.0f, s1 = 0.0f;
#pragma unroll
        for (int mt = 0; mt < 3; ++mt)
#pragma unroll
            for (int r = 0; r < 4; ++r) {
                float z = acc[mt][r] + tbv[mt][r];   // row = quad*4+r (+16*mt), col = point
                float h = fmaxf(z, 0.01f * z);       // leaky relu
                s0 = fmaf(h, w2a[mt][r], s0);
                s1 = fmaf(h, w2b[mt][r], s1);
            }
        s0 += __shfl_xor(s0, 16, 64);
        s0 += __shfl_xor(s0, 32, 64);
        s1 += __shfl_xor(s1, 16, 64);
        s1 += __shfl_xor(s1, 32, 64);
        if (quad == 0) {
            int p = pbase + w * 64 + t * 16 + col;
            float o0 = 1.0f / (1.0f + __expf(-(s0 + b20)));
            float o1 = 1.0f / (1.0f + __expf(-(s1 + b21)));
            out[p] = make_float2(o0, o1);
        }
    }
}

extern "C" void kernel_launch(void* const* d_in, const int* in_sizes, int n_in,
                              void* d_out, int out_size, void* d_ws, size_t ws_size,
                              hipStream_t stream) {
    const float* coords = (const float*)d_in[0];
    const float* t_feat = (const float*)d_in[1];
    const float* emb0   = (const float*)d_in[2];
    const float* emb1   = (const float*)d_in[3];
    const float* emb2   = (const float*)d_in[4];
    const float* emb3   = (const float*)d_in[5];
    const float* W1     = (const float*)d_in[6];
    const float* b1     = (const float*)d_in[7];
    const float* W2     = (const float*)d_in[8];
    const float* b2     = (const float*)d_in[9];

    char* ws = (char*)d_ws;
    uint4* tab           = (uint4*)(ws + 0);            // 348160 texels * 16 B = 5570560
    unsigned short* bpk  = (unsigned short*)(ws + 5570560);  // 6144 B
    float* tbias         = (float*)(ws + 5576704);      // 1536 B
    float* w2pad         = (float*)(ws + 5578240);      // 384 B

    prep_kernel<<<1361, 256, 0, stream>>>(emb0, emb1, emb2, emb3, W1, b1, t_feat, W2,
                                          tab, bpk, tbias, w2pad);
    fused_kernel<<<8192, 256, 0, stream>>>((const float2*)coords, tab, (const uint4*)bpk,
                                           tbias, w2pad, b2, (float2*)d_out);
}